// Round 2
// baseline (1470.724 us; speedup 1.0000x reference)
//
#include <hip/hip_runtime.h>

// Char-LSTM (B=4096, T=40, H=256, V=128) on MI355X.
//
// Persistent blocks: 256 blocks x 16 batch rows, each block runs all 40 steps
// locally (batch rows independent across the scan -> no grid sync).
// Recurrent matmul h @ W_h via 3-pass split-precision bf16 MFMA 16x16x32
// (hi*Whi + lo*Whi + hi*Wlo ~= fp32). One-hot x-part + bias folded into a
// precomputed embedding table gathered per (char, col).
//
// Column permutation trick: packed col pcol = wv*128 + f*16 + n maps to
// original gate col (f&3)*256 + wv*32 + (f>>2)*16 + n, so each wave owns all
// FOUR gates of its own 32 hidden units -> LSTM cell update runs entirely
// in the MFMA D-fragment register layout (no z staging in LDS, no cross-wave
// exchange). h is written back to LDS in exact A-fragment order so next
// step's A-loads are linear conflict-free ds_read_b128.

#define SEQ     40
#define VCH     128
#define HID     256
#define GATES   1024
#define BTILE   16
#define NBLK    256
#define THREADS 512

typedef __attribute__((ext_vector_type(8))) short short8;   // 8 bf16
typedef __attribute__((ext_vector_type(4))) float f32x4;

#define MFMA16(a, b, c) __builtin_amdgcn_mfma_f32_16x16x32_bf16((a), (b), (c), 0, 0, 0)

__device__ __forceinline__ unsigned short f2bf(float x) {
    unsigned u = __float_as_uint(x);
    return (unsigned short)((u + 0x7FFFu + ((u >> 16) & 1u)) >> 16);   // RNE
}
__device__ __forceinline__ float bf2f(unsigned short b) {
    return __uint_as_float(((unsigned)b) << 16);
}
__device__ __forceinline__ float sigm(float x) {
    return 1.0f / (1.0f + __expf(-x));
}
__device__ __forceinline__ float tanh_fast(float x) {
    float e = __expf(2.0f * x);
    return 1.0f - 2.0f / (e + 1.0f);   // exact limits at +-inf
}

// ---------------------------------------------------------------------------
// ws layout (bytes):
//   Whi  ushort[262144]  @ 0         (512 KB)  recurrent W hi, B-frag packed
//   Wlo  ushort[262144]  @ 512K      (512 KB)  recurrent W lo
//   Wdhi ushort[32768]   @ 1M        ( 64 KB)  dense W hi
//   Wdlo ushort[32768]   @ 1M+64K    ( 64 KB)  dense W lo
//   Emb  float [131072]  @ 1M+128K   (512 KB)  Emb[ch][pcol] = W_x[ch,oc]+b[oc]
// total 1.63 MB
// ---------------------------------------------------------------------------

// lstm pack idx = (((wv*8+f)*8+kc)*64+lane)*8+j
//   orig col = (f&3)*256 + wv*32 + (f>>2)*16 + (lane&15)
//   k        = kc*32 + (lane>>4)*8 + j
__global__ void pack_all(const float* __restrict__ W_lstm,
                         const float* __restrict__ b_lstm,
                         const float* __restrict__ W_dense,
                         unsigned short* __restrict__ Whi,
                         unsigned short* __restrict__ Wlo,
                         unsigned short* __restrict__ Wdhi,
                         unsigned short* __restrict__ Wdlo,
                         float* __restrict__ Emb) {
    int idx = blockIdx.x * blockDim.x + threadIdx.x;
    if (idx < 262144) {
        int j = idx & 7, lane = (idx >> 3) & 63, kc = (idx >> 9) & 7;
        int f = (idx >> 12) & 7, wv = idx >> 15;
        int oc = (f & 3) * 256 + wv * 32 + (f >> 2) * 16 + (lane & 15);
        int k  = kc * 32 + (lane >> 4) * 8 + j;
        float w = W_lstm[(size_t)(VCH + k) * GATES + oc];
        unsigned short hi = f2bf(w);
        Whi[idx] = hi;
        Wlo[idx] = f2bf(w - bf2f(hi));
    } else if (idx < 262144 + 32768) {
        int i2 = idx - 262144;
        int j = i2 & 7, lane = (i2 >> 3) & 63, kc = (i2 >> 9) & 7, f = i2 >> 12;
        int col = f * 16 + (lane & 15);
        int k   = kc * 32 + (lane >> 4) * 8 + j;
        float w = W_dense[(size_t)k * VCH + col];
        unsigned short hi = f2bf(w);
        Wdhi[i2] = hi;
        Wdlo[i2] = f2bf(w - bf2f(hi));
    } else if (idx < 262144 + 32768 + 131072) {
        int i3 = idx - (262144 + 32768);
        int pcol = i3 & 1023, ch = i3 >> 10;
        int wv = pcol >> 7, f = (pcol >> 4) & 7, n = pcol & 15;
        int oc = (f & 3) * 256 + wv * 32 + (f >> 2) * 16 + n;
        Emb[i3] = W_lstm[(size_t)ch * GATES + oc] + b_lstm[oc];
    }
}

__global__ __launch_bounds__(THREADS, 2)
void lstm_main(const int* __restrict__ inputs,
               const unsigned short* __restrict__ Whi,
               const unsigned short* __restrict__ Wlo,
               const unsigned short* __restrict__ Wdhi,
               const unsigned short* __restrict__ Wdlo,
               const float* __restrict__ Emb,
               const float* __restrict__ b_dense,
               float* __restrict__ out) {
    __shared__ __align__(16) unsigned short h_hi[4096];   // A-frag packed, 8 KB
    __shared__ __align__(16) unsigned short h_lo[4096];   // 8 KB
    __shared__ int chs[SEQ][BTILE];                       // 2.5 KB

    const int tid  = threadIdx.x;
    const int lane = tid & 63;
    const int wv   = tid >> 6;        // wave 0..7 -> units [wv*32, wv*32+32)
    const int n    = lane & 15;
    const int kq   = lane >> 4;
    const int b0   = blockIdx.x * BTILE;

    for (int i = tid; i < SEQ * BTILE; i += THREADS) {
        int row = i & (BTILE - 1), t = i >> 4;
        chs[t][row] = inputs[(size_t)(b0 + row) * SEQ + t];
    }
    for (int i = tid; i < 4096; i += THREADS) { h_hi[i] = 0; h_lo[i] = 0; }

    const unsigned short* wbh = Whi + (size_t)wv * 32768 + (size_t)lane * 8;
    const unsigned short* wbl = Wlo + (size_t)wv * 32768 + (size_t)lane * 8;
    const float* embbase = Emb + wv * 128 + n;   // + ch*1024 + f*16

    float c_st[8];
#pragma unroll
    for (int i = 0; i < 8; ++i) c_st[i] = 0.0f;

    __syncthreads();

    for (int t = 0; t < SEQ; ++t) {
        // ---- A-fragments (linear, conflict-free b128) ----------------------
        short8 ahi[8], alo[8];
#pragma unroll
        for (int kc = 0; kc < 8; ++kc) {
            ahi[kc] = *(const short8*)&h_hi[(kc * 64 + lane) * 8];
            alo[kc] = *(const short8*)&h_lo[(kc * 64 + lane) * 8];
        }
        // ---- per-step embedding gather (consumed only after MFMAs) --------
        int ch[4];
#pragma unroll
        for (int r = 0; r < 4; ++r) ch[r] = chs[t][kq * 4 + r];
        float gv[8][4];
#pragma unroll
        for (int f = 0; f < 8; ++f)
#pragma unroll
            for (int r = 0; r < 4; ++r)
                gv[f][r] = embbase[(size_t)ch[r] * GATES + f * 16];

        __syncthreads();   // all A-reads done before anyone overwrites h

        // ---- 3-pass MFMA: z_rec = h @ W_h ---------------------------------
        f32x4 acc[8];
#pragma unroll
        for (int f = 0; f < 8; ++f) acc[f] = (f32x4){0.f, 0.f, 0.f, 0.f};
#pragma unroll
        for (int kc = 0; kc < 8; ++kc) {
#pragma unroll
            for (int f = 0; f < 8; ++f) {
                short8 bh = *(const short8*)(wbh + f * 4096 + kc * 512);
                short8 bl = *(const short8*)(wbl + f * 4096 + kc * 512);
                acc[f] = MFMA16(ahi[kc], bh, acc[f]);
                acc[f] = MFMA16(alo[kc], bh, acc[f]);
                acc[f] = MFMA16(ahi[kc], bl, acc[f]);
            }
        }

        // ---- in-register LSTM cell update ---------------------------------
        // lane owns (row = kq*4+r, unit = wv*32 + hf*16 + n); gates at
        // acc[hf*4 + {0,1,2,3}] = i,j,f,o
#pragma unroll
        for (int hf = 0; hf < 2; ++hf) {
#pragma unroll
            for (int r = 0; r < 4; ++r) {
                float zi = acc[hf * 4 + 0][r] + gv[hf * 4 + 0][r];
                float zj = acc[hf * 4 + 1][r] + gv[hf * 4 + 1][r];
                float zf = acc[hf * 4 + 2][r] + gv[hf * 4 + 2][r];
                float zo = acc[hf * 4 + 3][r] + gv[hf * 4 + 3][r];
                float cc = sigm(zf + 1.0f) * c_st[hf * 4 + r]
                         + sigm(zi) * tanh_fast(zj);
                c_st[hf * 4 + r] = cc;
                float hh = sigm(zo) * tanh_fast(cc);
                unsigned short hb = f2bf(hh);
                // write h at A-frag position of (row=kq*4+r, k=wv*32+hf*16+n)
                int pos = (wv * 64 + (hf * 2 + (n >> 3)) * 16 + kq * 4 + r) * 8
                        + (n & 7);
                h_hi[pos] = hb;
                h_lo[pos] = f2bf(hh - bf2f(hb));
            }
        }
        __syncthreads();   // h complete before next step's A-reads
    }

    // ---- final dense: out = h_f @ W_dense + b_dense (3-pass MFMA) ---------
    {
        f32x4 dacc = (f32x4){0.f, 0.f, 0.f, 0.f};
        const unsigned short* dbh = Wdhi + (size_t)wv * 4096 + (size_t)lane * 8;
        const unsigned short* dbl = Wdlo + (size_t)wv * 4096 + (size_t)lane * 8;
#pragma unroll
        for (int kc = 0; kc < 8; ++kc) {
            short8 ah = *(const short8*)&h_hi[(kc * 64 + lane) * 8];
            short8 al = *(const short8*)&h_lo[(kc * 64 + lane) * 8];
            short8 bh = *(const short8*)(dbh + kc * 512);
            short8 bl = *(const short8*)(dbl + kc * 512);
            dacc = MFMA16(ah, bh, dacc);
            dacc = MFMA16(al, bh, dacc);
            dacc = MFMA16(ah, bl, dacc);
        }
        float bd = b_dense[wv * 16 + n];
#pragma unroll
        for (int r = 0; r < 4; ++r) {
            out[(size_t)(b0 + kq * 4 + r) * VCH + wv * 16 + n] = dacc[r] + bd;
        }
    }
}

extern "C" void kernel_launch(void* const* d_in, const int* in_sizes, int n_in,
                              void* d_out, int out_size, void* d_ws, size_t ws_size,
                              hipStream_t stream) {
    const int*   inputs  = (const int*)d_in[0];
    const float* W_lstm  = (const float*)d_in[1];
    const float* b_lstm  = (const float*)d_in[2];
    const float* W_dense = (const float*)d_in[3];
    const float* b_dense = (const float*)d_in[4];
    float* out = (float*)d_out;

    unsigned short* Whi  = (unsigned short*)d_ws;
    unsigned short* Wlo  = Whi + 262144;
    unsigned short* Wdhi = Wlo + 262144;
    unsigned short* Wdlo = Wdhi + 32768;
    float*          Emb  = (float*)(Wdlo + 32768);

    const int total = 262144 + 32768 + 131072;
    hipLaunchKernelGGL(pack_all, dim3((total + 255) / 256), dim3(256), 0, stream,
                       W_lstm, b_lstm, W_dense, Whi, Wlo, Wdhi, Wdlo, Emb);
    hipLaunchKernelGGL(lstm_main, dim3(NBLK), dim3(THREADS), 0, stream,
                       inputs, Whi, Wlo, Wdhi, Wdlo, Emb, b_dense, out);
}

// Round 3
// 1040.551 us; speedup vs baseline: 1.4134x; 1.4134x over previous
//
#include <hip/hip_runtime.h>

// Char-LSTM (B=4096, T=40, H=256, V=128) on MI355X — weight-stationary design.
//
// Round-2 post-mortem: weight re-streaming (1MB x 256 blocks x 40 steps) with
// 2 waves/SIMD and no in-flight depth => latency-serialized, 1435us.
// Round-3: weights live in LDS (128KB slice per block, loaded once); blocks
// exchange the small h state through a 4MB ping-pong buffer in d_ws with a
// custom grid barrier per step (cooperative launch).
//
// Partition: grid 256 = 8 col-slices (cs) x 32 row-groups (rg, 128 rows).
// Block (cs,rg): computes z[:, cs*128..+128] for its 128 rows, i.e. all four
// gates of hidden units cs*32..cs*32+32 (column permutation f = hf*4 + g).
// After the cell update it owns h[:, cs*32..+32] for its rows and publishes
// them; the next step needs all 256 k of h -> read back after grid barrier.
//
// h exchange format: u32 = (bf16_hi << 16) | bf16_lo  (RNE hi + residual lo),
// same 3-pass split precision as round 2 (verified absmax 4.9e-4).
// Coherence: h stores are relaxed AGENT-scope atomics (write-through past the
// per-XCD L2); barrier exit does an ACQUIRE load (emits cache invalidate) so
// normal vectorized A-loads after the barrier observe fresh data.

#define SEQ     40
#define VCH     128
#define HID     256
#define GATES   1024
#define NBLK    256
#define THREADS 512

typedef __attribute__((ext_vector_type(8))) short short8;   // 8 bf16
typedef __attribute__((ext_vector_type(4))) float f32x4;
typedef __attribute__((ext_vector_type(4))) unsigned int uint4v;

#define MFMA16(a, b, c) __builtin_amdgcn_mfma_f32_16x16x32_bf16((a), (b), (c), 0, 0, 0)

__device__ __forceinline__ unsigned short f2bf(float x) {
    unsigned u = __float_as_uint(x);
    return (unsigned short)((u + 0x7FFFu + ((u >> 16) & 1u)) >> 16);   // RNE
}
__device__ __forceinline__ float bf2f(unsigned short b) {
    return __uint_as_float(((unsigned)b) << 16);
}
__device__ __forceinline__ float sigm(float x) {
    return 1.0f / (1.0f + __expf(-x));
}
__device__ __forceinline__ float tanh_fast(float x) {
    float e = __expf(2.0f * x);
    return 1.0f - 2.0f / (e + 1.0f);   // exact limits at +-inf
}

// ---------------------------------------------------------------------------
// ws layout (bytes):
//   Whi   ushort[262144] @ 0        (512 KB) recurrent W hi, frag-packed, cs-major
//   Wlo   ushort[262144] @ 512K     (512 KB)
//   Wdhi  ushort[32768]  @ 1024K    ( 64 KB) dense W hi
//   Wdlo  ushort[32768]  @ 1088K    ( 64 KB)
//   Emb   float[131072]  @ 1152K    (512 KB) Emb[ch][pcol] = W_x[ch,oc]+b[oc]
//   hbuf  uint[2][4096*256] @ 1664K (8 MB)   ping-pong packed h
//   bar   int[2]          @ 9856K   (count, generation)
// ---------------------------------------------------------------------------

__global__ void pack_all(const float* __restrict__ W_lstm,
                         const float* __restrict__ b_lstm,
                         const float* __restrict__ W_dense,
                         unsigned short* __restrict__ Whi,
                         unsigned short* __restrict__ Wlo,
                         unsigned short* __restrict__ Wdhi,
                         unsigned short* __restrict__ Wdlo,
                         float* __restrict__ Emb,
                         int* __restrict__ bar) {
    int idx = blockIdx.x * blockDim.x + threadIdx.x;
    if (idx == 0) { bar[0] = 0; bar[1] = 0; }
    if (idx < 262144) {
        // idx = (((cs*8+f)*8+kc)*64+lane)*8+j
        int j = idx & 7, lane = (idx >> 3) & 63, kc = (idx >> 9) & 7;
        int f = (idx >> 12) & 7, cs = idx >> 15;
        int oc = (f & 3) * 256 + cs * 32 + (f >> 2) * 16 + (lane & 15);
        int k  = kc * 32 + (lane >> 4) * 8 + j;
        float w = W_lstm[(size_t)(VCH + k) * GATES + oc];
        unsigned short hi = f2bf(w);
        Whi[idx] = hi;
        Wlo[idx] = f2bf(w - bf2f(hi));
    } else if (idx < 262144 + 32768) {
        int i2 = idx - 262144;
        int j = i2 & 7, lane = (i2 >> 3) & 63, kc = (i2 >> 9) & 7, f = i2 >> 12;
        int col = f * 16 + (lane & 15);
        int k   = kc * 32 + (lane >> 4) * 8 + j;
        float w = W_dense[(size_t)k * VCH + col];
        unsigned short hi = f2bf(w);
        Wdhi[i2] = hi;
        Wdlo[i2] = f2bf(w - bf2f(hi));
    } else if (idx < 262144 + 32768 + 131072) {
        int i3 = idx - (262144 + 32768);
        int pcol = i3 & 1023, ch = i3 >> 10;
        int cs = pcol >> 7, f = (pcol >> 4) & 7, n = pcol & 15;
        int oc = (f & 3) * 256 + cs * 32 + (f >> 2) * 16 + n;
        Emb[i3] = W_lstm[(size_t)ch * GATES + oc] + b_lstm[oc];
    }
}

__device__ __forceinline__ void gridbar(int* bar) {
    __syncthreads();   // all waves' vmem drained (compiler emits vmcnt(0))
    if (threadIdx.x == 0) {
        int g = __hip_atomic_load(&bar[1], __ATOMIC_RELAXED, __HIP_MEMORY_SCOPE_AGENT);
        int prev = __hip_atomic_fetch_add(&bar[0], 1, __ATOMIC_RELAXED, __HIP_MEMORY_SCOPE_AGENT);
        if (prev == NBLK - 1) {
            __hip_atomic_store(&bar[0], 0, __ATOMIC_RELAXED, __HIP_MEMORY_SCOPE_AGENT);
            __hip_atomic_store(&bar[1], g + 1, __ATOMIC_RELEASE, __HIP_MEMORY_SCOPE_AGENT);
            // one acquire to invalidate our own stale L1/L2 too
            (void)__hip_atomic_load(&bar[1], __ATOMIC_ACQUIRE, __HIP_MEMORY_SCOPE_AGENT);
        } else {
            while (__hip_atomic_load(&bar[1], __ATOMIC_ACQUIRE, __HIP_MEMORY_SCOPE_AGENT) == g)
                __builtin_amdgcn_s_sleep(2);
        }
    }
    __syncthreads();
}

__device__ __forceinline__ void unpack_a(uint4v u0, uint4v u1, short8& hi, short8& lo) {
    union { uint4v u; short8 s; } ch, cl;
    ch.u = (uint4v){ (u0[0] >> 16) | (u0[1] & 0xFFFF0000u),
                     (u0[2] >> 16) | (u0[3] & 0xFFFF0000u),
                     (u1[0] >> 16) | (u1[1] & 0xFFFF0000u),
                     (u1[2] >> 16) | (u1[3] & 0xFFFF0000u) };
    cl.u = (uint4v){ (u0[0] & 0xFFFFu) | (u0[1] << 16),
                     (u0[2] & 0xFFFFu) | (u0[3] << 16),
                     (u1[0] & 0xFFFFu) | (u1[1] << 16),
                     (u1[2] & 0xFFFFu) | (u1[3] << 16) };
    hi = ch.s;
    lo = cl.s;
}

__global__ __launch_bounds__(THREADS, 2)
void lstm_main(const int* __restrict__ inputs,
               const unsigned short* __restrict__ Whi,
               const unsigned short* __restrict__ Wlo,
               const unsigned short* __restrict__ Wdhi,
               const unsigned short* __restrict__ Wdlo,
               const float* __restrict__ Emb,
               const float* __restrict__ b_dense,
               unsigned int* __restrict__ hbuf,
               int* __restrict__ bar,
               float* __restrict__ out) {
    __shared__ __align__(16) unsigned short wsh[32768];   // 64 KB  W slice hi
    __shared__ __align__(16) unsigned short wsl[32768];   // 64 KB  W slice lo
    __shared__ int chs[SEQ * 128];                        // 20 KB

    const int tid  = threadIdx.x;
    const int lane = tid & 63;
    const int w    = tid >> 6;       // wave 0..7 -> rows rw..rw+16
    const int n    = lane & 15;
    const int kq   = lane >> 4;
    const int cs   = blockIdx.x & 7;       // col-slice
    const int rg   = blockIdx.x >> 3;      // row-group
    const int r0   = rg * 128;
    const int rw   = r0 + w * 16;

    // ---- stage weight slice into LDS (one-time) ---------------------------
    {
        const uint4v* gh = (const uint4v*)(Whi + (size_t)cs * 32768);
        const uint4v* gl = (const uint4v*)(Wlo + (size_t)cs * 32768);
        uint4v* lh = (uint4v*)wsh;
        uint4v* ll = (uint4v*)wsl;
        for (int i = tid; i < 4096; i += THREADS) { lh[i] = gh[i]; ll[i] = gl[i]; }
    }
    for (int i = tid; i < SEQ * 128; i += THREADS) {
        int row = i & 127, t = i >> 7;
        chs[t * 128 + row] = inputs[(size_t)(r0 + row) * SEQ + t];
    }
    // ---- zero our slice of hbuf[0] (agent-visible) ------------------------
    for (int i = tid; i < 128 * 32; i += THREADS) {
        int rr = i >> 5, cc = i & 31;
        __hip_atomic_store(&hbuf[(size_t)(r0 + rr) * HID + cs * 32 + cc], 0u,
                           __ATOMIC_RELAXED, __HIP_MEMORY_SCOPE_AGENT);
    }

    float c_st[8];
#pragma unroll
    for (int i = 0; i < 8; ++i) c_st[i] = 0.0f;

    gridbar(bar);   // hbuf[0] zeros visible everywhere; LDS ready (syncthreads inside)

#pragma unroll 1
    for (int t = 0; t < SEQ; ++t) {
        const unsigned int* hb = hbuf + (size_t)(t & 1) * 4096 * HID;
        unsigned int* hw = hbuf + (size_t)((t & 1) ^ 1) * 4096 * HID;

        // ---- A loads: this wave's 16 rows, packed u32, vectorized ---------
        const unsigned int* arow = hb + (size_t)(rw + n) * HID + kq * 8;
        uint4v araw[16];
#pragma unroll
        for (int kc = 0; kc < 8; ++kc) {
            araw[kc * 2]     = *(const uint4v*)(arow + kc * 32);
            araw[kc * 2 + 1] = *(const uint4v*)(arow + kc * 32 + 4);
        }
        // ---- per-step embedding gather ------------------------------------
        int ch[4];
#pragma unroll
        for (int r = 0; r < 4; ++r) ch[r] = chs[t * 128 + w * 16 + kq * 4 + r];
        float gv[8][4];
#pragma unroll
        for (int f = 0; f < 8; ++f)
#pragma unroll
            for (int r = 0; r < 4; ++r)
                gv[f][r] = Emb[(size_t)ch[r] * GATES + cs * 128 + f * 16 + n];

        // ---- 3-pass MFMA: z = h @ W_slice ---------------------------------
        f32x4 acc[8];
#pragma unroll
        for (int f = 0; f < 8; ++f) acc[f] = (f32x4){0.f, 0.f, 0.f, 0.f};
#pragma unroll
        for (int kc = 0; kc < 8; ++kc) {
            short8 ahi, alo;
            unpack_a(araw[kc * 2], araw[kc * 2 + 1], ahi, alo);
#pragma unroll
            for (int f = 0; f < 8; ++f) {
                short8 bh = *(const short8*)&wsh[(f * 8 + kc) * 512 + lane * 8];
                short8 bl = *(const short8*)&wsl[(f * 8 + kc) * 512 + lane * 8];
                acc[f] = MFMA16(ahi, bh, acc[f]);
                acc[f] = MFMA16(alo, bh, acc[f]);
                acc[f] = MFMA16(ahi, bl, acc[f]);
            }
        }

        // ---- in-register cell update; publish h (agent write-through) -----
        // lane owns (row = rw + kq*4 + r, unit = cs*32 + hf*16 + n)
#pragma unroll
        for (int hf = 0; hf < 2; ++hf) {
#pragma unroll
            for (int r = 0; r < 4; ++r) {
                float zi = acc[hf * 4 + 0][r] + gv[hf * 4 + 0][r];
                float zj = acc[hf * 4 + 1][r] + gv[hf * 4 + 1][r];
                float zf = acc[hf * 4 + 2][r] + gv[hf * 4 + 2][r];
                float zo = acc[hf * 4 + 3][r] + gv[hf * 4 + 3][r];
                float cc = sigm(zf + 1.0f) * c_st[hf * 4 + r]
                         + sigm(zi) * tanh_fast(zj);
                c_st[hf * 4 + r] = cc;
                float hh = sigm(zo) * tanh_fast(cc);
                unsigned short hi = f2bf(hh);
                unsigned short lo = f2bf(hh - bf2f(hi));
                unsigned int pk = ((unsigned int)hi << 16) | (unsigned int)lo;
                __hip_atomic_store(&hw[(size_t)(rw + kq * 4 + r) * HID + cs * 32 + hf * 16 + n],
                                   pk, __ATOMIC_RELAXED, __HIP_MEMORY_SCOPE_AGENT);
            }
        }
        gridbar(bar);
    }

    // ---- final dense: out[:, cs*16..+16] = h @ Wd + b (3-pass MFMA) -------
    {
        const unsigned int* hb = hbuf;   // t=39 wrote buf[0]
        const unsigned int* arow = hb + (size_t)(rw + n) * HID + kq * 8;
        f32x4 dacc = (f32x4){0.f, 0.f, 0.f, 0.f};
#pragma unroll
        for (int kc = 0; kc < 8; ++kc) {
            uint4v u0 = *(const uint4v*)(arow + kc * 32);
            uint4v u1 = *(const uint4v*)(arow + kc * 32 + 4);
            short8 ahi, alo;
            unpack_a(u0, u1, ahi, alo);
            short8 bh = *(const short8*)(Wdhi + (size_t)(cs * 8 + kc) * 512 + lane * 8);
            short8 bl = *(const short8*)(Wdlo + (size_t)(cs * 8 + kc) * 512 + lane * 8);
            dacc = MFMA16(ahi, bh, dacc);
            dacc = MFMA16(alo, bh, dacc);
            dacc = MFMA16(ahi, bl, dacc);
        }
        float bd = b_dense[cs * 16 + n];
#pragma unroll
        for (int r = 0; r < 4; ++r) {
            out[(size_t)(rw + kq * 4 + r) * VCH + cs * 16 + n] = dacc[r] + bd;
        }
    }
}

extern "C" void kernel_launch(void* const* d_in, const int* in_sizes, int n_in,
                              void* d_out, int out_size, void* d_ws, size_t ws_size,
                              hipStream_t stream) {
    const int*   inputs  = (const int*)d_in[0];
    const float* W_lstm  = (const float*)d_in[1];
    const float* b_lstm  = (const float*)d_in[2];
    const float* W_dense = (const float*)d_in[3];
    const float* b_dense = (const float*)d_in[4];
    float* out = (float*)d_out;

    char* ws = (char*)d_ws;
    unsigned short* Whi  = (unsigned short*)(ws);
    unsigned short* Wlo  = (unsigned short*)(ws + 524288);
    unsigned short* Wdhi = (unsigned short*)(ws + 1048576);
    unsigned short* Wdlo = (unsigned short*)(ws + 1114112);
    float*          Emb  = (float*)(ws + 1179648);
    unsigned int*   hbuf = (unsigned int*)(ws + 1703936);
    int*            bar  = (int*)(ws + 1703936 + 8388608);

    const int total = 262144 + 32768 + 131072;
    hipLaunchKernelGGL(pack_all, dim3((total + 255) / 256), dim3(256), 0, stream,
                       W_lstm, b_lstm, W_dense, Whi, Wlo, Wdhi, Wdlo, Emb, bar);

    void* args[] = { (void*)&inputs, (void*)&Whi, (void*)&Wlo, (void*)&Wdhi,
                     (void*)&Wdlo, (void*)&Emb, (void*)&b_dense, (void*)&hbuf,
                     (void*)&bar, (void*)&out };
    hipError_t err = hipLaunchCooperativeKernel((const void*)lstm_main, dim3(NBLK),
                                                dim3(THREADS), args, 0, stream);
    if (err != hipSuccess) {
        // fallback: 256 one-block-per-CU workgroups are de-facto co-resident
        hipLaunchKernelGGL(lstm_main, dim3(NBLK), dim3(THREADS), 0, stream,
                           inputs, Whi, Wlo, Wdhi, Wdlo, Emb, b_dense, hbuf, bar, out);
    }
}